// Round 4
// baseline (381.930 us; speedup 1.0000x reference)
//
#include <hip/hip_runtime.h>
#include <hip/hip_bf16.h>

// Problem constants
#define Bn 16
#define Tn 2048
#define Hn 256
#define Pn 256
#define Ln 64              // scan chunk length
#define NCn (Tn / Ln)      // 32 chunks

__device__ __forceinline__ float2 cmul(float2 a, float2 b) {
  return make_float2(fmaf(a.x, b.x, -(a.y * b.y)), fmaf(a.x, b.y, a.y * b.x));
}

// ---------------------------------------------------------------------------
// k_prep: fused parameter prep.
//   lam_bar[p] = exp(lam*step)          (written by block 0 only)
//   b_barT[h][p] = coef[p] * b_tilde[p][h],  coef = (lam_bar-1)/lam
//   cT[p][h]     = c_tilde[h][p]
// ---------------------------------------------------------------------------
__global__ void k_prep(const float* __restrict__ lam_re,
                       const float* __restrict__ lam_im,
                       const float* __restrict__ log_step,
                       const float* __restrict__ b_in,   // (P,H,2)
                       const float* __restrict__ c_in,   // (H,P,2)
                       float2* __restrict__ lam_bar,     // [P]
                       float2* __restrict__ b_barT,      // [H][P]
                       float2* __restrict__ cT) {        // [P][H]
  const int blk = blockIdx.x;   // h for b_barT, p for cT
  const int tid = threadIdx.x;  // p for b_barT, h for cT

  float s = expf(log_step[tid]);
  float re = lam_re[tid], im = lam_im[tid];
  float er = expf(re * s);
  float sn, cs;
  sincosf(im * s, &sn, &cs);
  float2 lb = make_float2(er * cs, er * sn);
  if (blk == 0) lam_bar[tid] = lb;

  float denom = re * re + im * im;
  float nx = lb.x - 1.0f, ny = lb.y;
  float2 coef = make_float2((nx * re + ny * im) / denom,
                            (ny * re - nx * im) / denom);

  // b_barT[h=blk][p=tid]
  float2 bt = make_float2(b_in[(tid * Hn + blk) * 2 + 0],
                          b_in[(tid * Hn + blk) * 2 + 1]);
  b_barT[blk * Pn + tid] = cmul(coef, bt);
  // cT[p=blk][h=tid]
  cT[blk * Hn + tid] = make_float2(c_in[(tid * Pn + blk) * 2 + 0],
                                   c_in[(tid * Pn + blk) * 2 + 1]);
}

// ---------------------------------------------------------------------------
// k_bu: bu[b][t][p] = sum_h u[b][t][h] * b_barT[h][p]   (complex)
// Block = (chunk, b): 64 t-rows x 256 p, K = 256 (h), 256 threads.
// Also emits per-chunk scan summary (A,B,C) per p.
// ---------------------------------------------------------------------------
struct SmemGemm {
  float sA[16][64];     // [kk][t]
  float2 sB[16][256];   // [kk][p]
};
struct SmemSum {
  float2 sSA[8][256];
  float2 sSB[8][256];
  float sSC[8][256];
};

__launch_bounds__(256)
__global__ void k_bu(const float* __restrict__ u,        // (B,T,H)
                     const int* __restrict__ mask,       // (B,T)
                     const float2* __restrict__ b_barT,  // [H][P]
                     const float2* __restrict__ lam_bar, // [P]
                     float2* __restrict__ bu,            // (B,T,P)
                     float4* __restrict__ sumAB,         // (B,NC,P)
                     float* __restrict__ sumC) {         // (B,NC,P)
  __shared__ union {
    SmemGemm g;
    SmemSum s;
  } sm;
  __shared__ int sMask[Ln];

  const int chunk = blockIdx.x, b = blockIdx.y;
  const int tid = threadIdx.x;
  const int tx = tid & 31, ty = tid >> 5;
  const int t0 = chunk * Ln;

  if (tid < Ln) sMask[tid] = mask[b * Tn + t0 + tid];

  float accR[8][8], accI[8][8];
#pragma unroll
  for (int i = 0; i < 8; i++)
#pragma unroll
    for (int j = 0; j < 8; j++) { accR[i][j] = 0.f; accI[i][j] = 0.f; }

  const float* uB = u + (size_t)(b * Tn + t0) * Hn;

  for (int k0 = 0; k0 < Hn; k0 += 16) {
    {
      int t = tid >> 2, q = tid & 3;
      float4 v = *reinterpret_cast<const float4*>(uB + t * Hn + k0 + q * 4);
      sm.g.sA[q * 4 + 0][t] = v.x;
      sm.g.sA[q * 4 + 1][t] = v.y;
      sm.g.sA[q * 4 + 2][t] = v.z;
      sm.g.sA[q * 4 + 3][t] = v.w;
    }
#pragma unroll
    for (int kk = 0; kk < 16; kk++)
      sm.g.sB[kk][tid] = b_barT[(k0 + kk) * Pn + tid];
    __syncthreads();

#pragma unroll
    for (int kk = 0; kk < 16; kk++) {
      float a[8];
      float2 bb[8];
#pragma unroll
      for (int i = 0; i < 8; i++) a[i] = sm.g.sA[kk][ty * 8 + i];
#pragma unroll
      for (int j = 0; j < 8; j++) bb[j] = sm.g.sB[kk][tx + j * 32];
#pragma unroll
      for (int i = 0; i < 8; i++)
#pragma unroll
        for (int j = 0; j < 8; j++) {
          accR[i][j] = fmaf(a[i], bb[j].x, accR[i][j]);
          accI[i][j] = fmaf(a[i], bb[j].y, accI[i][j]);
        }
    }
    __syncthreads();
  }

  float2* buB = bu + (size_t)(b * Tn + t0) * Pn;
#pragma unroll
  for (int i = 0; i < 8; i++)
#pragma unroll
    for (int j = 0; j < 8; j++)
      buB[(ty * 8 + i) * Pn + tx + j * 32] = make_float2(accR[i][j], accI[i][j]);

  float2 lamv[8];
#pragma unroll
  for (int j = 0; j < 8; j++) lamv[j] = lam_bar[tx + j * 32];

#pragma unroll
  for (int j = 0; j < 8; j++) {
    float2 A = make_float2(1.f, 0.f), Bv = make_float2(0.f, 0.f);
    float C = 0.f;
#pragma unroll
    for (int i = 0; i < 8; i++) {
      int m = sMask[ty * 8 + i];
      float2 lv = lamv[j];
      float2 buv = make_float2(accR[i][j], accI[i][j]);
      float2 nA = cmul(lv, A);
      float2 nB = cmul(lv, Bv);
      nB.x += buv.x; nB.y += buv.y;
      A = m ? lv : nA;
      Bv = m ? buv : nB;
      C = m ? 1.f : C;
    }
    sm.s.sSA[ty][tx + j * 32] = A;
    sm.s.sSB[ty][tx + j * 32] = Bv;
    sm.s.sSC[ty][tx + j * 32] = C;
  }
  __syncthreads();

  {
    int p = tid;
    float2 A = make_float2(1.f, 0.f), Bv = make_float2(0.f, 0.f);
    float C = 0.f;
#pragma unroll
    for (int k = 0; k < 8; k++) {
      float2 eA = sm.s.sSA[k][p];
      float2 eB = sm.s.sSB[k][p];
      float eC = sm.s.sSC[k][p];
      bool r = (eC != 0.f);
      float2 nA = cmul(eA, A);
      float2 nB = cmul(eA, Bv);
      nB.x += eB.x; nB.y += eB.y;
      A = r ? eA : nA;
      Bv = r ? eB : nB;
      C = r ? 1.f : C;
    }
    size_t o = ((size_t)(b * NCn + chunk)) * Pn + p;
    sumAB[o] = make_float4(A.x, A.y, Bv.x, Bv.y);
    sumC[o] = C;
  }
}

// ---------------------------------------------------------------------------
// k_scan: inter-chunk scan. grid = B blocks, 256 threads (p).
// ---------------------------------------------------------------------------
__global__ void k_scan(const float* __restrict__ carry_re,
                       const float* __restrict__ carry_im,
                       const float4* __restrict__ sumAB,
                       const float* __restrict__ sumC,
                       float2* __restrict__ xe) {
  int b = blockIdx.x, p = threadIdx.x;
  float2 x = make_float2(carry_re[b * Pn + p], carry_im[b * Pn + p]);
  for (int k = 0; k < NCn; k++) {
    size_t o = ((size_t)(b * NCn + k)) * Pn + p;
    xe[o] = x;
    float4 ab = sumAB[o];
    float C = sumC[o];
    float2 nx = cmul(make_float2(ab.x, ab.y), x);
    nx.x += ab.z; nx.y += ab.w;
    x = (C != 0.f) ? make_float2(ab.z, ab.w) : nx;
  }
}

// ---------------------------------------------------------------------------
// k_apply: within-chunk sequential scan, in-place bu -> xs.
// Writes x_T for the last chunk; layout controlled by xt_interleaved.
// ---------------------------------------------------------------------------
__launch_bounds__(256)
__global__ void k_apply(const int* __restrict__ mask,
                        const float2* __restrict__ lam_bar,
                        const float2* __restrict__ xe,
                        float2* __restrict__ bu,
                        float* __restrict__ out_xt,
                        int xt_interleaved) {
  int chunk = blockIdx.x, b = blockIdx.y, p = threadIdx.x;
  int t0 = chunk * Ln;
  float2 x = xe[((size_t)(b * NCn + chunk)) * Pn + p];
  float2 lam = lam_bar[p];
  float2* buB = bu + (size_t)(b * Tn + t0) * Pn;
  const int* mB = mask + b * Tn + t0;

  for (int j0 = 0; j0 < Ln; j0 += 8) {
    float2 v[8];
    int m[8];
#pragma unroll
    for (int q = 0; q < 8; q++) {
      v[q] = buB[(j0 + q) * Pn + p];
      m[q] = mB[j0 + q];
    }
#pragma unroll
    for (int q = 0; q < 8; q++) {
      float2 nx = cmul(lam, x);
      nx.x += v[q].x; nx.y += v[q].y;
      x = m[q] ? v[q] : nx;
      buB[(j0 + q) * Pn + p] = x;
    }
  }
  if (chunk == NCn - 1) {
    if (xt_interleaved) {
      out_xt[(b * Pn + p) * 2 + 0] = x.x;
      out_xt[(b * Pn + p) * 2 + 1] = x.y;
    } else {
      // harness compares x_t as float32 (real part) only
      out_xt[b * Pn + p] = x.x;
    }
  }
}

// ---------------------------------------------------------------------------
// k_y: y[bt][h] = Re( sum_p cT[p][h] * xs[bt][p] ) + d[h]*u[bt][h]
// ---------------------------------------------------------------------------
__launch_bounds__(512)
__global__ void k_y(const float2* __restrict__ xs,   // (B*T, P)
                    const float2* __restrict__ cT,   // [P][H]
                    const float* __restrict__ u,     // (B*T, H)
                    const float* __restrict__ dvec,  // (H)
                    float* __restrict__ y_out) {     // (B*T, H)
  __shared__ float2 sA[128][17];
  __shared__ float2 sBt[16][256];

  const int tid = threadIdx.x;
  const int tx = tid & 15, ty = tid >> 4;
  const int bt0 = blockIdx.x * 128;

  float acc[4][16];
#pragma unroll
  for (int i = 0; i < 4; i++)
#pragma unroll
    for (int j = 0; j < 16; j++) acc[i][j] = 0.f;

  for (int k0 = 0; k0 < Pn; k0 += 16) {
    {
      int r = tid >> 2, q = tid & 3;
      const float* src = (const float*)(xs + (size_t)(bt0 + r) * Pn + k0 + q * 4);
      float4 v0 = *reinterpret_cast<const float4*>(src);
      float4 v1 = *reinterpret_cast<const float4*>(src + 4);
      sA[r][q * 4 + 0] = make_float2(v0.x, v0.y);
      sA[r][q * 4 + 1] = make_float2(v0.z, v0.w);
      sA[r][q * 4 + 2] = make_float2(v1.x, v1.y);
      sA[r][q * 4 + 3] = make_float2(v1.z, v1.w);
    }
    {
      int kk = tid >> 5, seg = tid & 31;
      const float* csrc = (const float*)(cT + (size_t)(k0 + kk) * Hn + seg * 8);
      float4 c0 = *reinterpret_cast<const float4*>(csrc);
      float4 c1 = *reinterpret_cast<const float4*>(csrc + 4);
      float4 c2 = *reinterpret_cast<const float4*>(csrc + 8);
      float4 c3 = *reinterpret_cast<const float4*>(csrc + 12);
      sBt[kk][seg * 8 + 0] = make_float2(c0.x, c0.y);
      sBt[kk][seg * 8 + 1] = make_float2(c0.z, c0.w);
      sBt[kk][seg * 8 + 2] = make_float2(c1.x, c1.y);
      sBt[kk][seg * 8 + 3] = make_float2(c1.z, c1.w);
      sBt[kk][seg * 8 + 4] = make_float2(c2.x, c2.y);
      sBt[kk][seg * 8 + 5] = make_float2(c2.z, c2.w);
      sBt[kk][seg * 8 + 6] = make_float2(c3.x, c3.y);
      sBt[kk][seg * 8 + 7] = make_float2(c3.z, c3.w);
    }
    __syncthreads();

#pragma unroll
    for (int kk = 0; kk < 16; kk++) {
      float2 a[4];
      float2 bb[16];
#pragma unroll
      for (int i = 0; i < 4; i++) a[i] = sA[ty + i * 32][kk];
#pragma unroll
      for (int j = 0; j < 16; j++) bb[j] = sBt[kk][tx + j * 16];
#pragma unroll
      for (int i = 0; i < 4; i++)
#pragma unroll
        for (int j = 0; j < 16; j++) {
          acc[i][j] = fmaf(a[i].x, bb[j].x, acc[i][j]);
          acc[i][j] = fmaf(-a[i].y, bb[j].y, acc[i][j]);
        }
    }
    __syncthreads();
  }

#pragma unroll
  for (int i = 0; i < 4; i++) {
    int row = bt0 + ty + i * 32;
    const float* urow = u + (size_t)row * Hn;
    float* yrow = y_out + (size_t)row * Hn;
#pragma unroll
    for (int j = 0; j < 16; j++) {
      int h = tx + j * 16;
      yrow[h] = fmaf(dvec[h], urow[h], acc[i][j]);
    }
  }
}

// ---------------------------------------------------------------------------
extern "C" void kernel_launch(void* const* d_in, const int* in_sizes, int n_in,
                              void* d_out, int out_size, void* d_ws, size_t ws_size,
                              hipStream_t stream) {
  const float* inputs   = (const float*)d_in[0];  // (B,T,H)
  const int*   mask     = (const int*)d_in[1];    // (B,T)
  const float* carry_re = (const float*)d_in[2];  // (B,P)
  const float* carry_im = (const float*)d_in[3];  // (B,P)
  const float* lam_re   = (const float*)d_in[4];  // (P)
  const float* lam_im   = (const float*)d_in[5];  // (P)
  const float* b_in     = (const float*)d_in[6];  // (P,H,2)
  const float* c_in     = (const float*)d_in[7];  // (H,P,2)
  const float* d_vec    = (const float*)d_in[8];  // (H)
  const float* log_step = (const float*)d_in[9];  // (P)

  // Output layout adapts to how the harness flattened the complex64 x_t:
  //   real-only:    out_size == B*P   + B*T*H  -> x_t = Re only, y at B*P
  //   interleaved:  out_size == B*P*2 + B*T*H  -> x_t = (re,im) pairs, y at B*P*2
  const int y_elems = Bn * Tn * Hn;
  const int xt_elems = out_size - y_elems;           // 4096 (real) or 8192 (pairs)
  const int xt_interleaved = (xt_elems >= Bn * Pn * 2) ? 1 : 0;

  float* out = (float*)d_out;
  float* out_xt = out;
  float* out_y  = out + xt_elems;

  char* ws = (char*)d_ws;
  size_t off = 0;
  auto alloc = [&](size_t bytes) -> void* {
    void* ptr = ws + off;
    off += (bytes + 255) & ~(size_t)255;
    return ptr;
  };
  float2* bu      = (float2*)alloc((size_t)Bn * Tn * Pn * sizeof(float2)); // 64 MB
  float2* b_barT  = (float2*)alloc((size_t)Hn * Pn * sizeof(float2));
  float2* cT      = (float2*)alloc((size_t)Pn * Hn * sizeof(float2));
  float2* lam_bar = (float2*)alloc(Pn * sizeof(float2));
  float4* sumAB   = (float4*)alloc((size_t)Bn * NCn * Pn * sizeof(float4));
  float*  sumC    = (float*)alloc((size_t)Bn * NCn * Pn * sizeof(float));
  float2* xe      = (float2*)alloc((size_t)Bn * NCn * Pn * sizeof(float2));
  (void)ws_size; (void)in_sizes; (void)n_in;

  k_prep<<<256, 256, 0, stream>>>(lam_re, lam_im, log_step, b_in, c_in,
                                  lam_bar, b_barT, cT);
  k_bu<<<dim3(NCn, Bn), 256, 0, stream>>>(inputs, mask, b_barT, lam_bar, bu, sumAB, sumC);
  k_scan<<<Bn, 256, 0, stream>>>(carry_re, carry_im, sumAB, sumC, xe);
  k_apply<<<dim3(NCn, Bn), 256, 0, stream>>>(mask, lam_bar, xe, bu, out_xt, xt_interleaved);
  k_y<<<256, 512, 0, stream>>>(bu, cT, inputs, d_vec, out_y);
}

// Round 6
// 192.793 us; speedup vs baseline: 1.9810x; 1.9810x over previous
//
#include <hip/hip_runtime.h>
#include <hip/hip_bf16.h>

// Problem constants
#define Bn 16
#define Tn 2048
#define Hn 256
#define Pn 256
#define Ln 64              // scan chunk length
#define NCn (Tn / Ln)      // 32 chunks
#define BTn (Bn * Tn)      // 32768 rows
#define NB  (2 * Pn)       // 512: bu row length in floats (re/im interleaved: n=2p,2p+1)

// MFMA GEMM tiling
#define BM 128
#define BK 32
#define APAD 40            // padded LDS row length (bf16 elems); 80B, 16B-aligned

typedef __attribute__((ext_vector_type(8))) short short8;
typedef __attribute__((ext_vector_type(4))) float f32x4;

__device__ __forceinline__ unsigned short f2bf(float f) {
  unsigned u = __float_as_uint(f);
  return (unsigned short)((u + 0x7FFFu + ((u >> 16) & 1u)) >> 16);  // RNE
}

__device__ __forceinline__ float2 cmul(float2 a, float2 b) {
  return make_float2(fmaf(a.x, b.x, -(a.y * b.y)), fmaf(a.x, b.y, a.y * b.x));
}

// ---------------------------------------------------------------------------
// k_prep: lam_bar[p]; b_bfT[n=2p|2p+1][h] = bf16(Re/Im b_bar[p][h]);
//         c_bfT[h][n=2p|2p+1] = bf16(cr[h][p] / -ci[h][p])
// b_bfT is the transposed-B operand for k_bu (Bt[n][k=h]);
// c_bfT is the transposed-B operand for k_y  (Bt[n=h][k=2p]).
// ---------------------------------------------------------------------------
__global__ void k_prep(const float* __restrict__ lam_re,
                       const float* __restrict__ lam_im,
                       const float* __restrict__ log_step,
                       const float* __restrict__ b_in,   // (P,H,2)
                       const float* __restrict__ c_in,   // (H,P,2)
                       float2* __restrict__ lam_bar,     // [P]
                       unsigned short* __restrict__ b_bfT, // [512][256]
                       unsigned short* __restrict__ c_bfT) { // [256][512]
  const int blk = blockIdx.x;   // h for b-part, p for c-part
  const int tid = threadIdx.x;  // p for b-part, h for c-part

  float s = expf(log_step[tid]);
  float re = lam_re[tid], im = lam_im[tid];
  float er = expf(re * s);
  float sn, cs;
  sincosf(im * s, &sn, &cs);
  float2 lb = make_float2(er * cs, er * sn);
  if (blk == 0) lam_bar[tid] = lb;

  float denom = re * re + im * im;
  float nx = lb.x - 1.0f, ny = lb.y;
  float2 coef = make_float2((nx * re + ny * im) / denom,
                            (ny * re - nx * im) / denom);

  // b-part: h=blk, p=tid
  float2 bt = make_float2(b_in[(tid * Hn + blk) * 2 + 0],
                          b_in[(tid * Hn + blk) * 2 + 1]);
  float2 bb = cmul(coef, bt);
  b_bfT[(size_t)(2 * tid + 0) * Hn + blk] = f2bf(bb.x);
  b_bfT[(size_t)(2 * tid + 1) * Hn + blk] = f2bf(bb.y);

  // c-part: p=blk, h=tid
  float cr = c_in[(tid * Pn + blk) * 2 + 0];
  float ci = c_in[(tid * Pn + blk) * 2 + 1];
  c_bfT[(size_t)tid * NB + 2 * blk + 0] = f2bf(cr);
  c_bfT[(size_t)tid * NB + 2 * blk + 1] = f2bf(-ci);
}

// ---------------------------------------------------------------------------
// k_bu_mfma: bu[bt][n] = sum_h u[bt][h] * B[h][n],  B[h][2p]=Re(b_bar), [2p+1]=Im
// Grid (BTn/BM=256, NB/BM=4), 256 thr = 4 waves (2x2), 4x4 frags of 16x16x32.
// A staged fp32->bf16 on the fly; B staged from pre-transposed bf16.
// ---------------------------------------------------------------------------
__launch_bounds__(256)
__global__ void k_bu_mfma(const float* __restrict__ u,            // [BTn][Hn]
                          const unsigned short* __restrict__ bT,  // [NB][Hn]
                          float* __restrict__ bu) {               // [BTn][NB]
  __shared__ unsigned short sA[BM * APAD];
  __shared__ unsigned short sB[BM * APAD];
  const int tid = threadIdx.x;
  const int bm = blockIdx.x, bn = blockIdx.y;
  const int lane = tid & 63, wid = tid >> 6;
  const int wr = wid >> 1, wc = wid & 1;
  const int grp = lane >> 4, l15 = lane & 15;

  const f32x4 vzero = {0.f, 0.f, 0.f, 0.f};
  f32x4 acc[4][4];
#pragma unroll
  for (int i = 0; i < 4; i++)
#pragma unroll
    for (int j = 0; j < 4; j++) acc[i][j] = vzero;

  const int sr = tid >> 1, sseg = (tid & 1) * 16;
  const float* uRow = u + (size_t)(bm * BM + sr) * Hn + sseg;
  const unsigned short* bRow = bT + (size_t)(bn * BM + sr) * Hn + sseg;
  unsigned short* sAw = &sA[sr * APAD + sseg];
  unsigned short* sBw = &sB[sr * APAD + sseg];

  for (int k0 = 0; k0 < Hn; k0 += BK) {
    float4 v0 = *reinterpret_cast<const float4*>(uRow + k0);
    float4 v1 = *reinterpret_cast<const float4*>(uRow + k0 + 4);
    float4 v2 = *reinterpret_cast<const float4*>(uRow + k0 + 8);
    float4 v3 = *reinterpret_cast<const float4*>(uRow + k0 + 12);
    short8 q0 = *reinterpret_cast<const short8*>(bRow + k0);
    short8 q1 = *reinterpret_cast<const short8*>(bRow + k0 + 8);
    short8 p0, p1;
    p0[0] = (short)f2bf(v0.x); p0[1] = (short)f2bf(v0.y);
    p0[2] = (short)f2bf(v0.z); p0[3] = (short)f2bf(v0.w);
    p0[4] = (short)f2bf(v1.x); p0[5] = (short)f2bf(v1.y);
    p0[6] = (short)f2bf(v1.z); p0[7] = (short)f2bf(v1.w);
    p1[0] = (short)f2bf(v2.x); p1[1] = (short)f2bf(v2.y);
    p1[2] = (short)f2bf(v2.z); p1[3] = (short)f2bf(v2.w);
    p1[4] = (short)f2bf(v3.x); p1[5] = (short)f2bf(v3.y);
    p1[6] = (short)f2bf(v3.z); p1[7] = (short)f2bf(v3.w);
    *reinterpret_cast<short8*>(sAw) = p0;
    *reinterpret_cast<short8*>(sAw + 8) = p1;
    *reinterpret_cast<short8*>(sBw) = q0;
    *reinterpret_cast<short8*>(sBw + 8) = q1;
    __syncthreads();

    short8 af[4], bfr[4];
#pragma unroll
    for (int i = 0; i < 4; i++)
      af[i] = *reinterpret_cast<const short8*>(
          &sA[(wr * 64 + i * 16 + l15) * APAD + grp * 8]);
#pragma unroll
    for (int j = 0; j < 4; j++)
      bfr[j] = *reinterpret_cast<const short8*>(
          &sB[(wc * 64 + j * 16 + l15) * APAD + grp * 8]);
#pragma unroll
    for (int i = 0; i < 4; i++)
#pragma unroll
      for (int j = 0; j < 4; j++)
        acc[i][j] = __builtin_amdgcn_mfma_f32_16x16x32_bf16(af[i], bfr[j],
                                                            acc[i][j], 0, 0, 0);
    __syncthreads();
  }

  const int r0 = bm * BM + wr * 64 + grp * 4;
  const int c0 = bn * BM + wc * 64 + l15;
#pragma unroll
  for (int i = 0; i < 4; i++)
#pragma unroll
    for (int j = 0; j < 4; j++) {
#pragma unroll
      for (int r = 0; r < 4; r++)
        bu[(size_t)(r0 + i * 16 + r) * NB + (c0 + j * 16)] = acc[i][j][r];
    }
}

// ---------------------------------------------------------------------------
// k_sum: per-(b,chunk,p) scan summary (A,B,C) from bu. Grid (NCn,Bn), 256 thr.
// ---------------------------------------------------------------------------
__launch_bounds__(256)
__global__ void k_sum(const float2* __restrict__ bu,      // [BTn][Pn] complex
                      const int* __restrict__ mask,       // (B,T)
                      const float2* __restrict__ lam_bar, // [P]
                      float4* __restrict__ sumAB,         // (B,NC,P)
                      float* __restrict__ sumC) {         // (B,NC,P)
  const int chunk = blockIdx.x, b = blockIdx.y, p = threadIdx.x;
  const float2 lam = lam_bar[p];
  const float2* buB = bu + (size_t)(b * Tn + chunk * Ln) * Pn;
  const int* mB = mask + b * Tn + chunk * Ln;

  float2 A = make_float2(1.f, 0.f), Bv = make_float2(0.f, 0.f);
  float C = 0.f;
  for (int t = 0; t < Ln; t++) {
    int m = mB[t];
    float2 v = buB[t * Pn + p];
    float2 nA = cmul(lam, A);
    float2 nB = cmul(lam, Bv);
    nB.x += v.x; nB.y += v.y;
    A = m ? lam : nA;
    Bv = m ? v : nB;
    C = m ? 1.f : C;
  }
  size_t o = ((size_t)(b * NCn + chunk)) * Pn + p;
  sumAB[o] = make_float4(A.x, A.y, Bv.x, Bv.y);
  sumC[o] = C;
}

// ---------------------------------------------------------------------------
// k_scan: inter-chunk scan. grid = B blocks, 256 threads (p).
// ---------------------------------------------------------------------------
__global__ void k_scan(const float* __restrict__ carry_re,
                       const float* __restrict__ carry_im,
                       const float4* __restrict__ sumAB,
                       const float* __restrict__ sumC,
                       float2* __restrict__ xe) {
  int b = blockIdx.x, p = threadIdx.x;
  float2 x = make_float2(carry_re[b * Pn + p], carry_im[b * Pn + p]);
  for (int k = 0; k < NCn; k++) {
    size_t o = ((size_t)(b * NCn + k)) * Pn + p;
    xe[o] = x;
    float4 ab = sumAB[o];
    float C = sumC[o];
    float2 nx = cmul(make_float2(ab.x, ab.y), x);
    nx.x += ab.z; nx.y += ab.w;
    x = (C != 0.f) ? make_float2(ab.z, ab.w) : nx;
  }
}

// ---------------------------------------------------------------------------
// k_apply: within-chunk sequential scan, in-place bu -> xs (fp32).
// Writes x_T for the last chunk; layout controlled by xt_interleaved.
// ---------------------------------------------------------------------------
__launch_bounds__(256)
__global__ void k_apply(const int* __restrict__ mask,
                        const float2* __restrict__ lam_bar,
                        const float2* __restrict__ xe,
                        float2* __restrict__ bu,
                        float* __restrict__ out_xt,
                        int xt_interleaved) {
  int chunk = blockIdx.x, b = blockIdx.y, p = threadIdx.x;
  int t0 = chunk * Ln;
  float2 x = xe[((size_t)(b * NCn + chunk)) * Pn + p];
  float2 lam = lam_bar[p];
  float2* buB = bu + (size_t)(b * Tn + t0) * Pn;
  const int* mB = mask + b * Tn + t0;

  for (int j0 = 0; j0 < Ln; j0 += 8) {
    float2 v[8];
    int m[8];
#pragma unroll
    for (int q = 0; q < 8; q++) {
      v[q] = buB[(j0 + q) * Pn + p];
      m[q] = mB[j0 + q];
    }
#pragma unroll
    for (int q = 0; q < 8; q++) {
      float2 nx = cmul(lam, x);
      nx.x += v[q].x; nx.y += v[q].y;
      x = m[q] ? v[q] : nx;
      buB[(j0 + q) * Pn + p] = x;
    }
  }
  if (chunk == NCn - 1) {
    if (xt_interleaved) {
      out_xt[(b * Pn + p) * 2 + 0] = x.x;
      out_xt[(b * Pn + p) * 2 + 1] = x.y;
    } else {
      out_xt[b * Pn + p] = x.x;
    }
  }
}

// ---------------------------------------------------------------------------
// k_y_mfma: y[bt][h] = sum_k xs[bt][k]*C'[k][h] + d[h]*u[bt][h]
// xs = bu after apply (fp32, converted to bf16 in staging), K = NB = 512.
// Grid (BTn/BM=256, Hn/BM=2).
// ---------------------------------------------------------------------------
__launch_bounds__(256)
__global__ void k_y_mfma(const float* __restrict__ xs,           // [BTn][NB]
                         const unsigned short* __restrict__ cT,  // [Hn][NB]
                         const float* __restrict__ u,            // [BTn][Hn]
                         const float* __restrict__ dvec,         // [Hn]
                         float* __restrict__ y) {                // [BTn][Hn]
  __shared__ unsigned short sA[BM * APAD];
  __shared__ unsigned short sB[BM * APAD];
  const int tid = threadIdx.x;
  const int bm = blockIdx.x, bn = blockIdx.y;
  const int lane = tid & 63, wid = tid >> 6;
  const int wr = wid >> 1, wc = wid & 1;
  const int grp = lane >> 4, l15 = lane & 15;

  const f32x4 vzero = {0.f, 0.f, 0.f, 0.f};
  f32x4 acc[4][4];
#pragma unroll
  for (int i = 0; i < 4; i++)
#pragma unroll
    for (int j = 0; j < 4; j++) acc[i][j] = vzero;

  const int sr = tid >> 1, sseg = (tid & 1) * 16;
  const float* aRow = xs + (size_t)(bm * BM + sr) * NB + sseg;
  const unsigned short* bRow = cT + (size_t)(bn * BM + sr) * NB + sseg;
  unsigned short* sAw = &sA[sr * APAD + sseg];
  unsigned short* sBw = &sB[sr * APAD + sseg];

  for (int k0 = 0; k0 < NB; k0 += BK) {
    float4 v0 = *reinterpret_cast<const float4*>(aRow + k0);
    float4 v1 = *reinterpret_cast<const float4*>(aRow + k0 + 4);
    float4 v2 = *reinterpret_cast<const float4*>(aRow + k0 + 8);
    float4 v3 = *reinterpret_cast<const float4*>(aRow + k0 + 12);
    short8 q0 = *reinterpret_cast<const short8*>(bRow + k0);
    short8 q1 = *reinterpret_cast<const short8*>(bRow + k0 + 8);
    short8 p0, p1;
    p0[0] = (short)f2bf(v0.x); p0[1] = (short)f2bf(v0.y);
    p0[2] = (short)f2bf(v0.z); p0[3] = (short)f2bf(v0.w);
    p0[4] = (short)f2bf(v1.x); p0[5] = (short)f2bf(v1.y);
    p0[6] = (short)f2bf(v1.z); p0[7] = (short)f2bf(v1.w);
    p1[0] = (short)f2bf(v2.x); p1[1] = (short)f2bf(v2.y);
    p1[2] = (short)f2bf(v2.z); p1[3] = (short)f2bf(v2.w);
    p1[4] = (short)f2bf(v3.x); p1[5] = (short)f2bf(v3.y);
    p1[6] = (short)f2bf(v3.z); p1[7] = (short)f2bf(v3.w);
    *reinterpret_cast<short8*>(sAw) = p0;
    *reinterpret_cast<short8*>(sAw + 8) = p1;
    *reinterpret_cast<short8*>(sBw) = q0;
    *reinterpret_cast<short8*>(sBw + 8) = q1;
    __syncthreads();

    short8 af[4], bfr[4];
#pragma unroll
    for (int i = 0; i < 4; i++)
      af[i] = *reinterpret_cast<const short8*>(
          &sA[(wr * 64 + i * 16 + l15) * APAD + grp * 8]);
#pragma unroll
    for (int j = 0; j < 4; j++)
      bfr[j] = *reinterpret_cast<const short8*>(
          &sB[(wc * 64 + j * 16 + l15) * APAD + grp * 8]);
#pragma unroll
    for (int i = 0; i < 4; i++)
#pragma unroll
      for (int j = 0; j < 4; j++)
        acc[i][j] = __builtin_amdgcn_mfma_f32_16x16x32_bf16(af[i], bfr[j],
                                                            acc[i][j], 0, 0, 0);
    __syncthreads();
  }

  const int r0 = bm * BM + wr * 64 + grp * 4;
  const int c0 = bn * BM + wc * 64 + l15;
#pragma unroll
  for (int i = 0; i < 4; i++)
#pragma unroll
    for (int j = 0; j < 4; j++) {
      int col = c0 + j * 16;
      float dv = dvec[col];
#pragma unroll
      for (int r = 0; r < 4; r++) {
        int row = r0 + i * 16 + r;
        y[(size_t)row * Hn + col] =
            fmaf(dv, u[(size_t)row * Hn + col], acc[i][j][r]);
      }
    }
}

// ---------------------------------------------------------------------------
extern "C" void kernel_launch(void* const* d_in, const int* in_sizes, int n_in,
                              void* d_out, int out_size, void* d_ws, size_t ws_size,
                              hipStream_t stream) {
  const float* inputs   = (const float*)d_in[0];  // (B,T,H)
  const int*   mask     = (const int*)d_in[1];    // (B,T)
  const float* carry_re = (const float*)d_in[2];  // (B,P)
  const float* carry_im = (const float*)d_in[3];  // (B,P)
  const float* lam_re   = (const float*)d_in[4];  // (P)
  const float* lam_im   = (const float*)d_in[5];  // (P)
  const float* b_in     = (const float*)d_in[6];  // (P,H,2)
  const float* c_in     = (const float*)d_in[7];  // (H,P,2)
  const float* d_vec    = (const float*)d_in[8];  // (H)
  const float* log_step = (const float*)d_in[9];  // (P)

  // Output layout adapts to how the harness flattened the complex64 x_t
  // (round-4 verified: real-only, y at offset B*P).
  const int y_elems = Bn * Tn * Hn;
  const int xt_elems = out_size - y_elems;
  const int xt_interleaved = (xt_elems >= Bn * Pn * 2) ? 1 : 0;

  float* out = (float*)d_out;
  float* out_xt = out;
  float* out_y  = out + xt_elems;

  char* ws = (char*)d_ws;
  size_t off = 0;
  auto alloc = [&](size_t bytes) -> void* {
    void* ptr = ws + off;
    off += (bytes + 255) & ~(size_t)255;
    return ptr;
  };
  float* bu              = (float*)alloc((size_t)BTn * NB * sizeof(float)); // 64 MB
  unsigned short* b_bfT  = (unsigned short*)alloc((size_t)NB * Hn * sizeof(short));
  unsigned short* c_bfT  = (unsigned short*)alloc((size_t)Hn * NB * sizeof(short));
  float2* lam_bar        = (float2*)alloc(Pn * sizeof(float2));
  float4* sumAB          = (float4*)alloc((size_t)Bn * NCn * Pn * sizeof(float4));
  float*  sumC           = (float*)alloc((size_t)Bn * NCn * Pn * sizeof(float));
  float2* xe             = (float2*)alloc((size_t)Bn * NCn * Pn * sizeof(float2));
  (void)ws_size; (void)in_sizes; (void)n_in;

  k_prep<<<256, 256, 0, stream>>>(lam_re, lam_im, log_step, b_in, c_in,
                                  lam_bar, b_bfT, c_bfT);
  k_bu_mfma<<<dim3(BTn / BM, NB / BM), 256, 0, stream>>>(inputs, b_bfT, bu);
  k_sum<<<dim3(NCn, Bn), 256, 0, stream>>>((const float2*)bu, mask, lam_bar,
                                           sumAB, sumC);
  k_scan<<<Bn, 256, 0, stream>>>(carry_re, carry_im, sumAB, sumC, xe);
  k_apply<<<dim3(NCn, Bn), 256, 0, stream>>>(mask, lam_bar, xe, (float2*)bu,
                                             out_xt, xt_interleaved);
  k_y_mfma<<<dim3(BTn / BM, Hn / BM), 256, 0, stream>>>(bu, c_bfT, inputs,
                                                        d_vec, out_y);
}